// Round 8
// baseline (365.328 us; speedup 1.0000x reference)
//
#include <hip/hip_runtime.h>
#include <hip/hip_bf16.h>

// Transformer block: B=32 T=512 C=512 H=8 D=64
// Round 12: A/B-isolate round 1's win. Round 0->1 bundled {swizzles} with
// {dbuf, which cost 3->2 blocks/CU}. m99/m100: dbuf ~= single-buffer at 4096^3;
// m114: co-resident blocks cover barrier drains. This round: SINGLE-buffered
// 2-phase GEMM (32 KB LDS, __launch_bounds__(256,3) -> 3 blocks/CU) + both
// swizzles kept. Everything else identical to round 1 (grids, attn, LN,
// transpose).

#define B_  32
#define T_  512
#define C_  512
#define H_  8
#define D_  64
#define BT  (B_*T_)      // 16384 rows
#define CF  2048         // 4*C

typedef __hip_bfloat16 bf16;
typedef __attribute__((ext_vector_type(8))) short bf16x8;   // 8 bf16 (4 VGPRs)
typedef __attribute__((ext_vector_type(4))) float f32x4;
typedef __attribute__((ext_vector_type(4))) short short4v;

__device__ __forceinline__ float bf2f(bf16 x) { return __bfloat162float(x); }
__device__ __forceinline__ bf16  f2bf(float x){ return __float2bfloat16(x); }
__device__ __forceinline__ short f2bf_bits(float f){
    bf16 h = __float2bfloat16(f);
    return *reinterpret_cast<short*>(&h);
}
__device__ __forceinline__ float bfbits2f(short s){
    unsigned u = ((unsigned)(unsigned short)s) << 16;
    return __uint_as_float(u);
}

#define AS_G __attribute__((address_space(1)))
#define AS_L __attribute__((address_space(3)))

// ---------------- All weight transposes in one launch ------------------------
__global__ __launch_bounds__(256) void transpose_all(const float* __restrict__ wq,
                                                     const float* __restrict__ wk,
                                                     const float* __restrict__ wv,
                                                     const float* __restrict__ wproj,
                                                     const float* __restrict__ w1,
                                                     const float* __restrict__ w2,
                                                     bf16* __restrict__ wt)
{
    const int t = blockIdx.x;
    const float* src; int K, Nn, k0, n0; size_t dstoff;
    if (t < 192) {
        const int which = t / 64, w = t % 64, hh = w >> 3, kt = w & 7;
        src = (which == 0 ? wq : which == 1 ? wk : wv) + (size_t)hh * 512 * 64;
        K = 512; Nn = 64; k0 = kt * 64; n0 = 0;
        dstoff = (size_t)(which * 512 + hh * 64) * 512;
    } else if (t < 256) {
        const int i = t - 192;
        src = wproj; K = 512; Nn = 512; n0 = (i & 7) * 64; k0 = (i >> 3) * 64;
        dstoff = (size_t)1536 * 512;
    } else if (t < 512) {
        const int i = t - 256;
        src = w1; K = 512; Nn = 2048; n0 = (i & 31) * 64; k0 = (i >> 5) * 64;
        dstoff = (size_t)2048 * 512;
    } else {
        const int i = t - 512;
        src = w2; K = 2048; Nn = 512; n0 = (i & 7) * 64; k0 = (i >> 3) * 64;
        dstoff = (size_t)2048 * 512 + (size_t)2048 * 512;
    }

    __shared__ float tl[64][65];
    const int tid = threadIdx.x;
    #pragma unroll
    for (int j = 0; j < 16; ++j) {
        const int e = j * 256 + tid, r = e >> 6, c = e & 63;
        tl[r][c] = src[(size_t)(k0 + r) * Nn + n0 + c];
    }
    __syncthreads();
    #pragma unroll
    for (int j = 0; j < 16; ++j) {
        const int e = j * 256 + tid, n = e >> 6, kk = e & 63;
        wt[dstoff + (size_t)(n0 + n) * K + k0 + kk] = f2bf(tl[kk][n]);
    }
}

// ---------------- LayerNorm: one block per row (C=512), 256 threads ----------
__global__ __launch_bounds__(256) void ln_kernel(const float* __restrict__ x,
                                                 const float* __restrict__ g,
                                                 const float* __restrict__ b,
                                                 bf16* __restrict__ out)
{
    const int row = blockIdx.x;
    const int tid = threadIdx.x;
    const float* xr = x + (size_t)row * C_;
    float v0 = xr[tid], v1 = xr[tid + 256];

    __shared__ float red[4];

    float s = v0 + v1;
    #pragma unroll
    for (int off = 32; off > 0; off >>= 1) s += __shfl_down(s, off, 64);
    if ((tid & 63) == 0) red[tid >> 6] = s;
    __syncthreads();
    const float mean = (red[0] + red[1] + red[2] + red[3]) * (1.0f / C_);
    __syncthreads();

    float d0 = v0 - mean, d1 = v1 - mean;
    float vs = d0 * d0 + d1 * d1;
    #pragma unroll
    for (int off = 32; off > 0; off >>= 1) vs += __shfl_down(vs, off, 64);
    if ((tid & 63) == 0) red[tid >> 6] = vs;
    __syncthreads();
    const float var  = (red[0] + red[1] + red[2] + red[3]) * (1.0f / C_);
    const float rstd = rsqrtf(var + 1e-5f);

    bf16* orow = out + (size_t)row * C_;
    orow[tid]       = f2bf(d0 * rstd * g[tid]       + b[tid]);
    orow[tid + 256] = f2bf(d1 * rstd * g[tid + 256] + b[tid + 256]);
}

// ---------------- MFMA GEMM: single-buffered 2-phase (m97 structure) ---------
// C[M,N] = A[M,K](bf16) * Bt[N,K](bf16)^T.  128x128 tile, BK=64, 256 thr =
// 4 waves (2x2 of 64x64). LDS 32 KB -> 3 blocks/CU (__launch_bounds__(256,3));
// per K-step: [barrier] STAGE(k) [barrier=vmcnt drain] compute. Co-resident
// blocks (12 waves/CU) cover each other's drains (m114). 16B chunks XOR-8
// swizzled; C^T accumulation (mfma(b,a)); QKV v-third normal orientation.
// Bijective XCD swizzle (all grids %8==0).
template<bool QKV, bool RELU, bool OUT_BF16>
__global__ __launch_bounds__(256, 3) void mfma_gemm(const bf16* __restrict__ A,
                                                    const bf16* __restrict__ Bt,
                                                    const float* __restrict__ bias,
                                                    const float* __restrict__ res,
                                                    void* __restrict__ outp,
                                                    int N, int K)
{
    __shared__ __align__(16) bf16 As[128 * 64];
    __shared__ __align__(16) bf16 Bs[128 * 64];

    const int tid  = threadIdx.x;
    const int wave = tid >> 6, lane = tid & 63;
    const int l16  = lane & 15, quad = lane >> 4;
    const int wm   = wave >> 1, wn = wave & 1;

    const int nwg = gridDim.x * gridDim.y;
    int bid = blockIdx.y * gridDim.x + blockIdx.x;
    bid = (bid & 7) * (nwg >> 3) + (bid >> 3);        // bijective XCD swizzle
    const int tn = (bid % gridDim.x) * 128;
    const int tm = (bid / gridDim.x) * 128;
    const bool vblk = QKV && (tn >= 1024);            // v third of merged QKV

    f32x4 acc[4][4];
    #pragma unroll
    for (int i = 0; i < 4; ++i)
        #pragma unroll
        for (int j = 0; j < 4; ++j) acc[i][j] = (f32x4){0.f, 0.f, 0.f, 0.f};

    for (int k0 = 0; k0 < K; k0 += 64) {
        __syncthreads();                               // protect prev tile reads
        #pragma unroll
        for (int j = 0; j < 4; ++j) {
            const int g = j * 256 + tid;
            const int row = g >> 3, phys = g & 7;
            const int c = phys ^ (row & 7);            // logical 16B chunk
            __builtin_amdgcn_global_load_lds((const AS_G void*)(A  + (size_t)(tm + row) * K + k0 + c * 8),
                                             (AS_L void*)&As[(size_t)g * 8], 16, 0, 0);
            __builtin_amdgcn_global_load_lds((const AS_G void*)(Bt + (size_t)(tn + row) * K + k0 + c * 8),
                                             (AS_L void*)&Bs[(size_t)g * 8], 16, 0, 0);
        }
        __syncthreads();                               // vmcnt drain -> visible

        #pragma unroll
        for (int half = 0; half < 2; ++half) {
            bf16x8 af[4], bfr[4];
            #pragma unroll
            for (int mf = 0; mf < 4; ++mf) {
                const int r = wm * 64 + mf * 16 + l16;
                const int p = (half * 4 + quad) ^ (r & 7);
                af[mf] = *(const bf16x8*)&As[r * 64 + p * 8];
            }
            #pragma unroll
            for (int nf = 0; nf < 4; ++nf) {
                const int r = wn * 64 + nf * 16 + l16;
                const int p = (half * 4 + quad) ^ (r & 7);
                bfr[nf] = *(const bf16x8*)&Bs[r * 64 + p * 8];
            }
            if (vblk) {
                #pragma unroll
                for (int mf = 0; mf < 4; ++mf)
                    #pragma unroll
                    for (int nf = 0; nf < 4; ++nf)
                        acc[mf][nf] = __builtin_amdgcn_mfma_f32_16x16x32_bf16(af[mf], bfr[nf], acc[mf][nf], 0, 0, 0);
            } else {
                #pragma unroll
                for (int mf = 0; mf < 4; ++mf)
                    #pragma unroll
                    for (int nf = 0; nf < 4; ++nf)
                        acc[mf][nf] = __builtin_amdgcn_mfma_f32_16x16x32_bf16(bfr[nf], af[mf], acc[mf][nf], 0, 0, 0);
            }
        }
    }

    if (QKV) {
        bf16* qkv = (bf16*)outp;                 // q base; k at +8M elems, v at +16M
        if (!vblk) {
            const int which = tn >> 9;           // 0=q, 1=k
            bf16* dst = qkv + (size_t)which * (8u << 20);
            #pragma unroll
            for (int mf = 0; mf < 4; ++mf) {
                const int m = tm + wm * 64 + mf * 16 + l16;   // token (C^T: col=m)
                const int bb = m >> 9, t = m & 511;
                #pragma unroll
                for (int nf = 0; nf < 4; ++nf) {
                    const int nb = tn + wn * 64 + nf * 16 + quad * 4;
                    const int hh = (nb >> 6) & 7, dd = nb & 63;
                    short4v pk;
                    #pragma unroll
                    for (int r = 0; r < 4; ++r) pk[r] = f2bf_bits(acc[mf][nf][r]);
                    *(short4v*)&dst[((size_t)(bb * 8 + hh) * 512 + t) * 64 + dd] = pk;
                }
            }
        } else {
            bf16* dst = qkv + (size_t)2 * (8u << 20);
            #pragma unroll
            for (int mf = 0; mf < 4; ++mf) {
                const int mb = tm + wm * 64 + mf * 16 + quad * 4;   // token base
                const int bb = mb >> 9, t = mb & 511;
                #pragma unroll
                for (int nf = 0; nf < 4; ++nf) {
                    const int n = tn + wn * 64 + nf * 16 + l16;
                    const int hh = (n >> 6) & 7, dd = n & 63;
                    short4v pk;
                    #pragma unroll
                    for (int r = 0; r < 4; ++r) pk[r] = f2bf_bits(acc[mf][nf][r]);
                    *(short4v*)&dst[((size_t)(bb * 8 + hh) * 64 + dd) * 512 + t] = pk;
                }
            }
        }
    } else {
        #pragma unroll
        for (int mf = 0; mf < 4; ++mf) {
            const int m = tm + wm * 64 + mf * 16 + l16;             // C^T: col=m
            #pragma unroll
            for (int nf = 0; nf < 4; ++nf) {
                const int nb = tn + wn * 64 + nf * 16 + quad * 4;   // 4 consecutive n
                f32x4 a = acc[mf][nf];
                if (bias) a += *(const f32x4*)&bias[nb];
                if (RELU) {
                    #pragma unroll
                    for (int r = 0; r < 4; ++r) a[r] = fmaxf(a[r], 0.0f);
                }
                if (res)  a += *(const f32x4*)&res[(size_t)m * N + nb];
                if (OUT_BF16) {
                    short4v pk;
                    #pragma unroll
                    for (int r = 0; r < 4; ++r) pk[r] = f2bf_bits(a[r]);
                    *(short4v*)&((bf16*)outp)[(size_t)m * N + nb] = pk;
                } else {
                    *(f32x4*)&((float*)outp)[(size_t)m * N + nb] = a;
                }
            }
        }
    }
}

// ---------------- Flash attention: qt-paired, dbuf global_load_lds -----------
#define ATTN_TILE(qa, m_i, l_i, Of, qw, qtT)                                          \
  do {                                                                                \
    f32x4 Sf[4];                                                                      \
    _Pragma("unroll")                                                                 \
    for (int kf = 0; kf < 4; ++kf) {                                                  \
        const int row = kf * 16 + l16;                                                \
        bf16x8 b0 = *(const bf16x8*)&Ks[cur][row * 64 + ((quad ^ (row & 7)) * 8)];    \
        bf16x8 b1 = *(const bf16x8*)&Ks[cur][row * 64 + (((4 + quad) ^ (row & 7)) * 8)]; \
        f32x4 z = (f32x4){0.f, 0.f, 0.f, 0.f};                                        \
        z = __builtin_amdgcn_mfma_f32_16x16x32_bf16(qa[0], b0, z, 0, 0, 0);           \
        z = __builtin_amdgcn_mfma_f32_16x16x32_bf16(qa[1], b1, z, 0, 0, 0);           \
        Sf[kf] = z;                                                                   \
    }                                                                                 \
    if (kt == qtT) {                                                                  \
        _Pragma("unroll")                                                             \
        for (int kf = 0; kf < 4; ++kf)                                                \
            _Pragma("unroll")                                                         \
            for (int r = 0; r < 4; ++r)                                               \
                if (kt * 64 + kf * 16 + l16 > (qw) + quad * 4 + r) Sf[kf][r] = -1e30f;\
    }                                                                                 \
    float mnew[4], alpha[4];                                                          \
    _Pragma("unroll")                                                                 \
    for (int r = 0; r < 4; ++r) {                                                     \
        float v = fmaxf(fmaxf(Sf[0][r], Sf[1][r]), fmaxf(Sf[2][r], Sf[3][r]));        \
        v = fmaxf(v, __shfl_xor(v, 1, 64));                                           \
        v = fmaxf(v, __shfl_xor(v, 2, 64));                                           \
        v = fmaxf(v, __shfl_xor(v, 4, 64));                                           \
        v = fmaxf(v, __shfl_xor(v, 8, 64));                                           \
        mnew[r]   = fmaxf(m_i[r], v);                                                 \
        alpha[r]  = __expf(m_i[r] - mnew[r]);                                         \
        m_i[r]    = mnew[r];                                                          \
    }                                                                                 \
    float rs[4] = {0.f, 0.f, 0.f, 0.f};                                               \
    _Pragma("unroll")                                                                 \
    for (int kf = 0; kf < 4; ++kf) {                                                  \
        _Pragma("unroll")                                                             \
        for (int r = 0; r < 4; ++r) {                                                 \
            float p = __expf(Sf[kf][r] - mnew[r]);                                    \
            rs[r] += p;                                                               \
            Pw[wave][quad * 4 + r][kf * 16 + l16] = f2bf(p);                          \
        }                                                                             \
    }                                                                                 \
    _Pragma("unroll")                                                                 \
    for (int r = 0; r < 4; ++r) {                                                     \
        rs[r] += __shfl_xor(rs[r], 1, 64);                                            \
        rs[r] += __shfl_xor(rs[r], 2, 64);                                            \
        rs[r] += __shfl_xor(rs[r], 4, 64);                                            \
        rs[r] += __shfl_xor(rs[r], 8, 64);                                            \
        l_i[r] = l_i[r] * alpha[r] + rs[r];                                           \
    }                                                                                 \
    _Pragma("unroll")                                                                 \
    for (int f = 0; f < 4; ++f)                                                       \
        _Pragma("unroll")                                                             \
        for (int r = 0; r < 4; ++r)                                                   \
            Of[f][r] *= alpha[r];                                                     \
    bf16x8 pa0 = *(const bf16x8*)&Pw[wave][l16][quad * 8];                            \
    bf16x8 pa1 = *(const bf16x8*)&Pw[wave][l16][32 + quad * 8];                       \
    _Pragma("unroll")                                                                 \
    for (int f = 0; f < 4; ++f) {                                                     \
        const int vrow = f * 16 + l16;                                                \
        bf16x8 vb0 = *(const bf16x8*)&Vt[cur][vrow * 64 + ((quad ^ (vrow & 7)) * 8)]; \
        bf16x8 vb1 = *(const bf16x8*)&Vt[cur][vrow * 64 + (((4 + quad) ^ (vrow & 7)) * 8)]; \
        Of[f] = __builtin_amdgcn_mfma_f32_16x16x32_bf16(pa0, vb0, Of[f], 0, 0, 0);    \
        Of[f] = __builtin_amdgcn_mfma_f32_16x16x32_bf16(pa1, vb1, Of[f], 0, 0, 0);    \
    }                                                                                 \
  } while (0)

__global__ __launch_bounds__(256, 2) void attn_kernel(const bf16* __restrict__ q,
                                                      const bf16* __restrict__ kM,
                                                      const bf16* __restrict__ vT,
                                                      bf16* __restrict__ o)
{
    __shared__ __align__(16) bf16 Ks[2][64 * 64];
    __shared__ __align__(16) bf16 Vt[2][64 * 64];
    __shared__ __align__(16) bf16 Pw[4][16][72];

    const int tid  = threadIdx.x;
    const int wave = tid >> 6, lane = tid & 63;
    const int l16  = lane & 15, quad = lane >> 4;

    const int nwg = gridDim.x * gridDim.y;
    int bid = blockIdx.y * gridDim.x + blockIdx.x;
    bid = (bid & 7) * (nwg >> 3) + (bid >> 3);
    const int pair = bid & 3;
    const int bh   = bid >> 2;

    const int qt0 = pair, qt1 = 7 - pair;
    const int qw0 = qt0 * 64 + wave * 16;
    const int qw1 = qt1 * 64 + wave * 16;

    const float scale = 0.04419417382415922f;  // C^-0.5 (reference uses n_embd)
    bf16x8 qa0[2], qa1[2];
    #pragma unroll
    for (int c = 0; c < 2; ++c) {
        bf16x8 t0 = *(const bf16x8*)(q + ((size_t)bh * T_ + qw0 + l16) * 64 + c * 32 + quad * 8);
        bf16x8 t1 = *(const bf16x8*)(q + ((size_t)bh * T_ + qw1 + l16) * 64 + c * 32 + quad * 8);
        #pragma unroll
        for (int j = 0; j < 8; ++j) {
            t0[j] = f2bf_bits(bfbits2f(t0[j]) * scale);
            t1[j] = f2bf_bits(bfbits2f(t1[j]) * scale);
        }
        qa0[c] = t0; qa1[c] = t1;
    }

    float m0[4], l0[4], m1[4], l1[4];
    f32x4 O0[4], O1[4];
    #pragma unroll
    for (int r = 0; r < 4; ++r) { m0[r] = -1e30f; l0[r] = 0.f; m1[r] = -1e30f; l1[r] = 0.f; }
    #pragma unroll
    for (int f = 0; f < 4; ++f) { O0[f] = (f32x4){0.f,0.f,0.f,0.f}; O1[f] = (f32x4){0.f,0.f,0.f,0.f}; }

    auto STAGE = [&](int buf, int kt) {
        const int k0 = kt * 64;
        #pragma unroll
        for (int j = 0; j < 2; ++j) {
            const int g = j * 256 + tid;
            const int row = g >> 3, phys = g & 7;
            const int c = phys ^ (row & 7);
            __builtin_amdgcn_global_load_lds((const AS_G void*)(kM + ((size_t)bh * T_ + k0 + row) * 64 + c * 8),
                                             (AS_L void*)&Ks[buf][(size_t)g * 8], 16, 0, 0);
            __builtin_amdgcn_global_load_lds((const AS_G void*)(vT + ((size_t)bh * 64 + row) * T_ + k0 + c * 8),
                                             (AS_L void*)&Vt[buf][(size_t)g * 8], 16, 0, 0);
        }
    };

    STAGE(0, 0);
    __syncthreads();

    int cur = 0;
    for (int kt = 0; kt <= qt1; ++kt) {
        if (kt < qt1) STAGE(cur ^ 1, kt + 1);

        if (kt <= qt0) ATTN_TILE(qa0, m0, l0, O0, qw0, qt0);
        ATTN_TILE(qa1, m1, l1, O1, qw1, qt1);

        __syncthreads();
        cur ^= 1;
    }

    const int b = bh >> 3, hh = bh & 7;
    #pragma unroll
    for (int r = 0; r < 4; ++r) {
        const float inv0 = 1.0f / l0[r];
        const float inv1 = 1.0f / l1[r];
        const int t0 = qw0 + quad * 4 + r;
        const int t1 = qw1 + quad * 4 + r;
        #pragma unroll
        for (int f = 0; f < 4; ++f) {
            o[((size_t)b * T_ + t0) * C_ + hh * 64 + f * 16 + l16] = f2bf(O0[f][r] * inv0);
            o[((size_t)b * T_ + t1) * C_ + hh * 64 + f * 16 + l16] = f2bf(O1[f][r] * inv1);
        }
    }
}

// -----------------------------------------------------------------------------
extern "C" void kernel_launch(void* const* d_in, const int* in_sizes, int n_in,
                              void* d_out, int out_size, void* d_ws, size_t ws_size,
                              hipStream_t stream)
{
    const float* x     = (const float*)d_in[0];
    const float* wq    = (const float*)d_in[1];
    const float* wk    = (const float*)d_in[2];
    const float* wv    = (const float*)d_in[3];
    const float* wproj = (const float*)d_in[4];
    const float* bproj = (const float*)d_in[5];
    const float* w1    = (const float*)d_in[6];
    const float* b1    = (const float*)d_in[7];
    const float* w2    = (const float*)d_in[8];
    const float* b2    = (const float*)d_in[9];
    const float* ln1g  = (const float*)d_in[10];
    const float* ln1b  = (const float*)d_in[11];
    const float* ln2g  = (const float*)d_in[12];
    const float* ln2b  = (const float*)d_in[13];

    // Workspace:
    //  [0,64M)    h,q,k,v (16 MB each) -> later mid (BT x 2048 bf16)
    //  [64,80M)   o (B,T,C bf16)
    //  [80,96M)   h2 (bf16)
    //  [96,102M)  Wt: qkvt[1536][512] | projt[512][512] | w1t[2048][512] | w2t[512][2048]
    //  x1 (f32) lives in d_out (same-thread RMW in final epilogue)
    char* ws = (char*)d_ws;
    bf16*  h    = (bf16*)(ws + 0);
    bf16*  q    = (bf16*)(ws + ((size_t)16 << 20));
    bf16*  k    = (bf16*)(ws + ((size_t)32 << 20));
    bf16*  v    = (bf16*)(ws + ((size_t)48 << 20));   // (B,H,D,T)
    bf16*  mid  = (bf16*)(ws + 0);
    bf16*  o    = (bf16*)(ws + ((size_t)64 << 20));
    bf16*  h2   = (bf16*)(ws + ((size_t)80 << 20));
    bf16*  wt   = (bf16*)(ws + ((size_t)96 << 20));
    bf16*  projt = wt + (size_t)1536 * 512;
    bf16*  w1t   = wt + (size_t)2048 * 512;
    bf16*  w2t   = wt + (size_t)4096 * 512;
    float* x1    = (float*)d_out;

    // 0. all weight transposes (f32 -> bf16, [N][K])
    transpose_all<<<768, 256, 0, stream>>>(wq, wk, wv, wproj, w1, w2, wt);

    // 1. h = LN1(x)
    ln_kernel<<<BT, 256, 0, stream>>>(x, ln1g, ln1b, h);

    // 2. q|k|v = h @ wqkv  (one N=1536 GEMM; v written (B,H,D,T))
    mfma_gemm<true,  false, true ><<<dim3(12, 128), 256, 0, stream>>>(h, wt, nullptr, nullptr, q, 1536, 512);

    // 3. o = flash-attn(q,k,v) -> (B,T,C); qt-paired grid
    attn_kernel<<<dim3(4, B_ * H_), 256, 0, stream>>>(q, k, v, o);

    // 4. x1 = x + o @ w_proj + b_proj   (x1 = d_out, f32)
    mfma_gemm<false, false, false><<<dim3(4, 128), 256, 0, stream>>>(o, projt, bproj, x, x1, 512, 512);

    // 5. h2 = LN2(x1)
    ln_kernel<<<BT, 256, 0, stream>>>(x1, ln2g, ln2b, h2);

    // 6. mid = relu(h2 @ w1 + b1)
    mfma_gemm<false, true,  true ><<<dim3(16, 128), 256, 0, stream>>>(h2, w1t, b1, nullptr, mid, 2048, 512);

    // 7. out = x1 + mid @ w2 + b2   (in-place on d_out)
    mfma_gemm<false, false, false><<<dim3(4, 128), 256, 0, stream>>>(mid, w2t, b2, x1, (float*)d_out, 512, 2048);
}

// Round 9
// 337.365 us; speedup vs baseline: 1.0829x; 1.0829x over previous
//
#include <hip/hip_runtime.h>
#include <hip/hip_bf16.h>

// Transformer block: B=32 T=512 C=512 H=8 D=64
// Round 13: consolidation. GEMM 2x2 A/B complete: {swz,dbuf} 2-phase 128^2 is
// the local optimum (65.3 us FFN1); single-buf 3blk/CU regressed (72.4), all
// counted-vmcnt/persistent restructures 67-73. Revert all GEMMs to round-1.
// Orthogonal adds this round:
//  - attn: s_setprio(1/0) around QK^T and PV MFMA clusters (m191: attn-only
//    +4-7%; nulls on barrier-locked GEMM, so GEMMs untouched).
//  - transpose_all + LN1 fused into one prep launch (independent work;
//    overlaps across CUs, saves a launch).
// LN2 unchanged (depends on proj output).

#define B_  32
#define T_  512
#define C_  512
#define H_  8
#define D_  64
#define BT  (B_*T_)      // 16384 rows
#define CF  2048         // 4*C

typedef __hip_bfloat16 bf16;
typedef __attribute__((ext_vector_type(8))) short bf16x8;   // 8 bf16 (4 VGPRs)
typedef __attribute__((ext_vector_type(4))) float f32x4;
typedef __attribute__((ext_vector_type(4))) short short4v;

__device__ __forceinline__ float bf2f(bf16 x) { return __bfloat162float(x); }
__device__ __forceinline__ bf16  f2bf(float x){ return __float2bfloat16(x); }
__device__ __forceinline__ short f2bf_bits(float f){
    bf16 h = __float2bfloat16(f);
    return *reinterpret_cast<short*>(&h);
}
__device__ __forceinline__ float bfbits2f(short s){
    unsigned u = ((unsigned)(unsigned short)s) << 16;
    return __uint_as_float(u);
}

#define AS_G __attribute__((address_space(1)))
#define AS_L __attribute__((address_space(3)))

// ---------------- prep: weight transposes (768 blocks) + LN1 (16384 blocks) --
// blockIdx.x < 768: transpose tile; else LN1 row = blockIdx.x - 768.
// Transposes: [0,192) qkv heads, [192,256) proj, [256,512) w1, [512,768) w2
// -> wt: qkvt[1536][512] | projt[512][512] | w1t[2048][512] | w2t[512][2048].
__global__ __launch_bounds__(256) void prep_kernel(const float* __restrict__ wq,
                                                   const float* __restrict__ wk,
                                                   const float* __restrict__ wv,
                                                   const float* __restrict__ wproj,
                                                   const float* __restrict__ w1,
                                                   const float* __restrict__ w2,
                                                   bf16* __restrict__ wt,
                                                   const float* __restrict__ x,
                                                   const float* __restrict__ g,
                                                   const float* __restrict__ b,
                                                   bf16* __restrict__ out)
{
    __shared__ float tl[64][65];
    const int tid = threadIdx.x;

    if (blockIdx.x >= 768) {
        // ---- LN1 path ----
        const int row = blockIdx.x - 768;
        const float* xr = x + (size_t)row * C_;
        float v0 = xr[tid], v1 = xr[tid + 256];

        float* red = &tl[0][0];

        float s = v0 + v1;
        #pragma unroll
        for (int off = 32; off > 0; off >>= 1) s += __shfl_down(s, off, 64);
        if ((tid & 63) == 0) red[tid >> 6] = s;
        __syncthreads();
        const float mean = (red[0] + red[1] + red[2] + red[3]) * (1.0f / C_);
        __syncthreads();

        float d0 = v0 - mean, d1 = v1 - mean;
        float vs = d0 * d0 + d1 * d1;
        #pragma unroll
        for (int off = 32; off > 0; off >>= 1) vs += __shfl_down(vs, off, 64);
        if ((tid & 63) == 0) red[tid >> 6] = vs;
        __syncthreads();
        const float var  = (red[0] + red[1] + red[2] + red[3]) * (1.0f / C_);
        const float rstd = rsqrtf(var + 1e-5f);

        bf16* orow = out + (size_t)row * C_;
        orow[tid]       = f2bf(d0 * rstd * g[tid]       + b[tid]);
        orow[tid + 256] = f2bf(d1 * rstd * g[tid + 256] + b[tid + 256]);
        return;
    }

    // ---- transpose path ----
    const int t = blockIdx.x;
    const float* src; int K, Nn, k0, n0; size_t dstoff;
    if (t < 192) {
        const int which = t / 64, w = t % 64, hh = w >> 3, kt = w & 7;
        src = (which == 0 ? wq : which == 1 ? wk : wv) + (size_t)hh * 512 * 64;
        K = 512; Nn = 64; k0 = kt * 64; n0 = 0;
        dstoff = (size_t)(which * 512 + hh * 64) * 512;
    } else if (t < 256) {
        const int i = t - 192;
        src = wproj; K = 512; Nn = 512; n0 = (i & 7) * 64; k0 = (i >> 3) * 64;
        dstoff = (size_t)1536 * 512;
    } else if (t < 512) {
        const int i = t - 256;
        src = w1; K = 512; Nn = 2048; n0 = (i & 31) * 64; k0 = (i >> 5) * 64;
        dstoff = (size_t)2048 * 512;
    } else {
        const int i = t - 512;
        src = w2; K = 2048; Nn = 512; n0 = (i & 7) * 64; k0 = (i >> 3) * 64;
        dstoff = (size_t)2048 * 512 + (size_t)2048 * 512;
    }

    #pragma unroll
    for (int j = 0; j < 16; ++j) {
        const int e = j * 256 + tid, r = e >> 6, c = e & 63;
        tl[r][c] = src[(size_t)(k0 + r) * Nn + n0 + c];
    }
    __syncthreads();
    #pragma unroll
    for (int j = 0; j < 16; ++j) {
        const int e = j * 256 + tid, n = e >> 6, kk = e & 63;
        wt[dstoff + (size_t)(n0 + n) * K + k0 + kk] = f2bf(tl[kk][n]);
    }
}

// ---------------- LayerNorm (LN2): one block per row (C=512) -----------------
__global__ __launch_bounds__(256) void ln_kernel(const float* __restrict__ x,
                                                 const float* __restrict__ g,
                                                 const float* __restrict__ b,
                                                 bf16* __restrict__ out)
{
    const int row = blockIdx.x;
    const int tid = threadIdx.x;
    const float* xr = x + (size_t)row * C_;
    float v0 = xr[tid], v1 = xr[tid + 256];

    __shared__ float red[4];

    float s = v0 + v1;
    #pragma unroll
    for (int off = 32; off > 0; off >>= 1) s += __shfl_down(s, off, 64);
    if ((tid & 63) == 0) red[tid >> 6] = s;
    __syncthreads();
    const float mean = (red[0] + red[1] + red[2] + red[3]) * (1.0f / C_);
    __syncthreads();

    float d0 = v0 - mean, d1 = v1 - mean;
    float vs = d0 * d0 + d1 * d1;
    #pragma unroll
    for (int off = 32; off > 0; off >>= 1) vs += __shfl_down(vs, off, 64);
    if ((tid & 63) == 0) red[tid >> 6] = vs;
    __syncthreads();
    const float var  = (red[0] + red[1] + red[2] + red[3]) * (1.0f / C_);
    const float rstd = rsqrtf(var + 1e-5f);

    bf16* orow = out + (size_t)row * C_;
    orow[tid]       = f2bf(d0 * rstd * g[tid]       + b[tid]);
    orow[tid + 256] = f2bf(d1 * rstd * g[tid + 256] + b[tid + 256]);
}

// ---------------- MFMA GEMM: round-1 dbuf 2-phase 128^2 (best known) ---------
// C[M,N] = A[M,K](bf16) * Bt[N,K](bf16)^T. 128x128 tile, BK=64, 256 thr =
// 4 waves (2x2 of 64x64). Double-buffered: STAGE(next) -> compute(cur) ->
// one barrier per K-step (its vmcnt(0) lands after ~300cy of ds_read+MFMA).
// 16B chunks XOR-8 swizzled (phys = log ^ (row&7)); C^T accumulation
// (mfma(b,a)); QKV v-third normal orientation. Bijective XCD swizzle.
template<bool QKV, bool RELU, bool OUT_BF16>
__global__ __launch_bounds__(256, 2) void mfma_gemm(const bf16* __restrict__ A,
                                                    const bf16* __restrict__ Bt,
                                                    const float* __restrict__ bias,
                                                    const float* __restrict__ res,
                                                    void* __restrict__ outp,
                                                    int N, int K)
{
    __shared__ __align__(16) bf16 As[2][128 * 64];
    __shared__ __align__(16) bf16 Bs[2][128 * 64];

    const int tid  = threadIdx.x;
    const int wave = tid >> 6, lane = tid & 63;
    const int l16  = lane & 15, quad = lane >> 4;
    const int wm   = wave >> 1, wn = wave & 1;

    const int nwg = gridDim.x * gridDim.y;
    int bid = blockIdx.y * gridDim.x + blockIdx.x;
    bid = (bid & 7) * (nwg >> 3) + (bid >> 3);
    const int tn = (bid % gridDim.x) * 128;
    const int tm = (bid / gridDim.x) * 128;
    const bool vblk = QKV && (tn >= 1024);     // v third of the merged QKV GEMM

    f32x4 acc[4][4];
    #pragma unroll
    for (int i = 0; i < 4; ++i)
        #pragma unroll
        for (int j = 0; j < 4; ++j) acc[i][j] = (f32x4){0.f, 0.f, 0.f, 0.f};

    auto STAGE = [&](int buf, int k0) {
        #pragma unroll
        for (int j = 0; j < 4; ++j) {
            const int g = j * 256 + tid;
            const int row = g >> 3, phys = g & 7;
            const int c = phys ^ (row & 7);          // logical 16B chunk
            __builtin_amdgcn_global_load_lds((const AS_G void*)(A  + (size_t)(tm + row) * K + k0 + c * 8),
                                             (AS_L void*)&As[buf][(size_t)g * 8], 16, 0, 0);
            __builtin_amdgcn_global_load_lds((const AS_G void*)(Bt + (size_t)(tn + row) * K + k0 + c * 8),
                                             (AS_L void*)&Bs[buf][(size_t)g * 8], 16, 0, 0);
        }
    };

    STAGE(0, 0);
    __syncthreads();

    int cur = 0;
    for (int k0 = 0; k0 < K; k0 += 64) {
        if (k0 + 64 < K) STAGE(cur ^ 1, k0 + 64);   // prefetch next tile

        #pragma unroll
        for (int half = 0; half < 2; ++half) {
            bf16x8 af[4], bfr[4];
            #pragma unroll
            for (int mf = 0; mf < 4; ++mf) {
                const int r = wm * 64 + mf * 16 + l16;
                const int p = (half * 4 + quad) ^ (r & 7);
                af[mf] = *(const bf16x8*)&As[cur][r * 64 + p * 8];
            }
            #pragma unroll
            for (int nf = 0; nf < 4; ++nf) {
                const int r = wn * 64 + nf * 16 + l16;
                const int p = (half * 4 + quad) ^ (r & 7);
                bfr[nf] = *(const bf16x8*)&Bs[cur][r * 64 + p * 8];
            }
            if (vblk) {
                #pragma unroll
                for (int mf = 0; mf < 4; ++mf)
                    #pragma unroll
                    for (int nf = 0; nf < 4; ++nf)
                        acc[mf][nf] = __builtin_amdgcn_mfma_f32_16x16x32_bf16(af[mf], bfr[nf], acc[mf][nf], 0, 0, 0);
            } else {
                #pragma unroll
                for (int mf = 0; mf < 4; ++mf)
                    #pragma unroll
                    for (int nf = 0; nf < 4; ++nf)
                        acc[mf][nf] = __builtin_amdgcn_mfma_f32_16x16x32_bf16(bfr[nf], af[mf], acc[mf][nf], 0, 0, 0);
            }
        }

        __syncthreads();
        cur ^= 1;
    }

    if (QKV) {
        bf16* qkv = (bf16*)outp;                 // q base; k at +8M elems, v at +16M
        if (!vblk) {
            const int which = tn >> 9;           // 0=q, 1=k
            bf16* dst = qkv + (size_t)which * (8u << 20);
            #pragma unroll
            for (int mf = 0; mf < 4; ++mf) {
                const int m = tm + wm * 64 + mf * 16 + l16;   // token (C^T: col=m)
                const int bb = m >> 9, t = m & 511;
                #pragma unroll
                for (int nf = 0; nf < 4; ++nf) {
                    const int nb = tn + wn * 64 + nf * 16 + quad * 4;
                    const int hh = (nb >> 6) & 7, dd = nb & 63;
                    short4v pk;
                    #pragma unroll
                    for (int r = 0; r < 4; ++r) pk[r] = f2bf_bits(acc[mf][nf][r]);
                    *(short4v*)&dst[((size_t)(bb * 8 + hh) * 512 + t) * 64 + dd] = pk;
                }
            }
        } else {
            bf16* dst = qkv + (size_t)2 * (8u << 20);
            #pragma unroll
            for (int mf = 0; mf < 4; ++mf) {
                const int mb = tm + wm * 64 + mf * 16 + quad * 4;   // token base
                const int bb = mb >> 9, t = mb & 511;
                #pragma unroll
                for (int nf = 0; nf < 4; ++nf) {
                    const int n = tn + wn * 64 + nf * 16 + l16;
                    const int hh = (n >> 6) & 7, dd = n & 63;
                    short4v pk;
                    #pragma unroll
                    for (int r = 0; r < 4; ++r) pk[r] = f2bf_bits(acc[mf][nf][r]);
                    *(short4v*)&dst[((size_t)(bb * 8 + hh) * 64 + dd) * 512 + t] = pk;
                }
            }
        }
    } else {
        #pragma unroll
        for (int mf = 0; mf < 4; ++mf) {
            const int m = tm + wm * 64 + mf * 16 + l16;             // C^T: col=m
            #pragma unroll
            for (int nf = 0; nf < 4; ++nf) {
                const int nb = tn + wn * 64 + nf * 16 + quad * 4;   // 4 consecutive n
                f32x4 a = acc[mf][nf];
                if (bias) a += *(const f32x4*)&bias[nb];
                if (RELU) {
                    #pragma unroll
                    for (int r = 0; r < 4; ++r) a[r] = fmaxf(a[r], 0.0f);
                }
                if (res)  a += *(const f32x4*)&res[(size_t)m * N + nb];
                if (OUT_BF16) {
                    short4v pk;
                    #pragma unroll
                    for (int r = 0; r < 4; ++r) pk[r] = f2bf_bits(a[r]);
                    *(short4v*)&((bf16*)outp)[(size_t)m * N + nb] = pk;
                } else {
                    *(f32x4*)&((float*)outp)[(size_t)m * N + nb] = a;
                }
            }
        }
    }
}

// ---------------- Flash attention: qt-paired + setprio around MFMA -----------
#define ATTN_TILE(qa, m_i, l_i, Of, qw, qtT)                                          \
  do {                                                                                \
    f32x4 Sf[4];                                                                      \
    __builtin_amdgcn_s_setprio(1);                                                    \
    _Pragma("unroll")                                                                 \
    for (int kf = 0; kf < 4; ++kf) {                                                  \
        const int row = kf * 16 + l16;                                                \
        bf16x8 b0 = *(const bf16x8*)&Ks[cur][row * 64 + ((quad ^ (row & 7)) * 8)];    \
        bf16x8 b1 = *(const bf16x8*)&Ks[cur][row * 64 + (((4 + quad) ^ (row & 7)) * 8)]; \
        f32x4 z = (f32x4){0.f, 0.f, 0.f, 0.f};                                        \
        z = __builtin_amdgcn_mfma_f32_16x16x32_bf16(qa[0], b0, z, 0, 0, 0);           \
        z = __builtin_amdgcn_mfma_f32_16x16x32_bf16(qa[1], b1, z, 0, 0, 0);           \
        Sf[kf] = z;                                                                   \
    }                                                                                 \
    __builtin_amdgcn_s_setprio(0);                                                    \
    if (kt == qtT) {                                                                  \
        _Pragma("unroll")                                                             \
        for (int kf = 0; kf < 4; ++kf)                                                \
            _Pragma("unroll")                                                         \
            for (int r = 0; r < 4; ++r)                                               \
                if (kt * 64 + kf * 16 + l16 > (qw) + quad * 4 + r) Sf[kf][r] = -1e30f;\
    }                                                                                 \
    float mnew[4], alpha[4];                                                          \
    _Pragma("unroll")                                                                 \
    for (int r = 0; r < 4; ++r) {                                                     \
        float v = fmaxf(fmaxf(Sf[0][r], Sf[1][r]), fmaxf(Sf[2][r], Sf[3][r]));        \
        v = fmaxf(v, __shfl_xor(v, 1, 64));                                           \
        v = fmaxf(v, __shfl_xor(v, 2, 64));                                           \
        v = fmaxf(v, __shfl_xor(v, 4, 64));                                           \
        v = fmaxf(v, __shfl_xor(v, 8, 64));                                           \
        mnew[r]   = fmaxf(m_i[r], v);                                                 \
        alpha[r]  = __expf(m_i[r] - mnew[r]);                                         \
        m_i[r]    = mnew[r];                                                          \
    }                                                                                 \
    float rs[4] = {0.f, 0.f, 0.f, 0.f};                                               \
    _Pragma("unroll")                                                                 \
    for (int kf = 0; kf < 4; ++kf) {                                                  \
        _Pragma("unroll")                                                             \
        for (int r = 0; r < 4; ++r) {                                                 \
            float p = __expf(Sf[kf][r] - mnew[r]);                                    \
            rs[r] += p;                                                               \
            Pw[wave][quad * 4 + r][kf * 16 + l16] = f2bf(p);                          \
        }                                                                             \
    }                                                                                 \
    _Pragma("unroll")                                                                 \
    for (int r = 0; r < 4; ++r) {                                                     \
        rs[r] += __shfl_xor(rs[r], 1, 64);                                            \
        rs[r] += __shfl_xor(rs[r], 2, 64);                                            \
        rs[r] += __shfl_xor(rs[r], 4, 64);                                            \
        rs[r] += __shfl_xor(rs[r], 8, 64);                                            \
        l_i[r] = l_i[r] * alpha[r] + rs[r];                                           \
    }                                                                                 \
    _Pragma("unroll")                                                                 \
    for (int f = 0; f < 4; ++f)                                                       \
        _Pragma("unroll")                                                             \
        for (int r = 0; r < 4; ++r)                                                   \
            Of[f][r] *= alpha[r];                                                     \
    bf16x8 pa0 = *(const bf16x8*)&Pw[wave][l16][quad * 8];                            \
    bf16x8 pa1 = *(const bf16x8*)&Pw[wave][l16][32 + quad * 8];                       \
    __builtin_amdgcn_s_setprio(1);                                                    \
    _Pragma("unroll")                                                                 \
    for (int f = 0; f < 4; ++f) {                                                     \
        const int vrow = f * 16 + l16;                                                \
        bf16x8 vb0 = *(const bf16x8*)&Vt[cur][vrow * 64 + ((quad ^ (vrow & 7)) * 8)]; \
        bf16x8 vb1 = *(const bf16x8*)&Vt[cur][vrow * 64 + (((4 + quad) ^ (vrow & 7)) * 8)]; \
        Of[f] = __builtin_amdgcn_mfma_f32_16x16x32_bf16(pa0, vb0, Of[f], 0, 0, 0);    \
        Of[f] = __builtin_amdgcn_mfma_f32_16x16x32_bf16(pa1, vb1, Of[f], 0, 0, 0);    \
    }                                                                                 \
    __builtin_amdgcn_s_setprio(0);                                                    \
  } while (0)

__global__ __launch_bounds__(256, 2) void attn_kernel(const bf16* __restrict__ q,
                                                      const bf16* __restrict__ kM,
                                                      const bf16* __restrict__ vT,
                                                      bf16* __restrict__ o)
{
    __shared__ __align__(16) bf16 Ks[2][64 * 64];
    __shared__ __align__(16) bf16 Vt[2][64 * 64];
    __shared__ __align__(16) bf16 Pw[4][16][72];

    const int tid  = threadIdx.x;
    const int wave = tid >> 6, lane = tid & 63;
    const int l16  = lane & 15, quad = lane >> 4;

    const int nwg = gridDim.x * gridDim.y;
    int bid = blockIdx.y * gridDim.x + blockIdx.x;
    bid = (bid & 7) * (nwg >> 3) + (bid >> 3);
    const int pair = bid & 3;
    const int bh   = bid >> 2;

    const int qt0 = pair, qt1 = 7 - pair;
    const int qw0 = qt0 * 64 + wave * 16;
    const int qw1 = qt1 * 64 + wave * 16;

    const float scale = 0.04419417382415922f;  // C^-0.5 (reference uses n_embd)
    bf16x8 qa0[2], qa1[2];
    #pragma unroll
    for (int c = 0; c < 2; ++c) {
        bf16x8 t0 = *(const bf16x8*)(q + ((size_t)bh * T_ + qw0 + l16) * 64 + c * 32 + quad * 8);
        bf16x8 t1 = *(const bf16x8*)(q + ((size_t)bh * T_ + qw1 + l16) * 64 + c * 32 + quad * 8);
        #pragma unroll
        for (int j = 0; j < 8; ++j) {
            t0[j] = f2bf_bits(bfbits2f(t0[j]) * scale);
            t1[j] = f2bf_bits(bfbits2f(t1[j]) * scale);
        }
        qa0[c] = t0; qa1[c] = t1;
    }

    float m0[4], l0[4], m1[4], l1[4];
    f32x4 O0[4], O1[4];
    #pragma unroll
    for (int r = 0; r < 4; ++r) { m0[r] = -1e30f; l0[r] = 0.f; m1[r] = -1e30f; l1[r] = 0.f; }
    #pragma unroll
    for (int f = 0; f < 4; ++f) { O0[f] = (f32x4){0.f,0.f,0.f,0.f}; O1[f] = (f32x4){0.f,0.f,0.f,0.f}; }

    auto STAGE = [&](int buf, int kt) {
        const int k0 = kt * 64;
        #pragma unroll
        for (int j = 0; j < 2; ++j) {
            const int g = j * 256 + tid;
            const int row = g >> 3, phys = g & 7;
            const int c = phys ^ (row & 7);
            __builtin_amdgcn_global_load_lds((const AS_G void*)(kM + ((size_t)bh * T_ + k0 + row) * 64 + c * 8),
                                             (AS_L void*)&Ks[buf][(size_t)g * 8], 16, 0, 0);
            __builtin_amdgcn_global_load_lds((const AS_G void*)(vT + ((size_t)bh * 64 + row) * T_ + k0 + c * 8),
                                             (AS_L void*)&Vt[buf][(size_t)g * 8], 16, 0, 0);
        }
    };

    STAGE(0, 0);
    __syncthreads();

    int cur = 0;
    for (int kt = 0; kt <= qt1; ++kt) {
        if (kt < qt1) STAGE(cur ^ 1, kt + 1);

        if (kt <= qt0) ATTN_TILE(qa0, m0, l0, O0, qw0, qt0);
        ATTN_TILE(qa1, m1, l1, O1, qw1, qt1);

        __syncthreads();
        cur ^= 1;
    }

    const int b = bh >> 3, hh = bh & 7;
    #pragma unroll
    for (int r = 0; r < 4; ++r) {
        const float inv0 = 1.0f / l0[r];
        const float inv1 = 1.0f / l1[r];
        const int t0 = qw0 + quad * 4 + r;
        const int t1 = qw1 + quad * 4 + r;
        #pragma unroll
        for (int f = 0; f < 4; ++f) {
            o[((size_t)b * T_ + t0) * C_ + hh * 64 + f * 16 + l16] = f2bf(O0[f][r] * inv0);
            o[((size_t)b * T_ + t1) * C_ + hh * 64 + f * 16 + l16] = f2bf(O1[f][r] * inv1);
        }
    }
}

// -----------------------------------------------------------------------------
extern "C" void kernel_launch(void* const* d_in, const int* in_sizes, int n_in,
                              void* d_out, int out_size, void* d_ws, size_t ws_size,
                              hipStream_t stream)
{
    const float* x     = (const float*)d_in[0];
    const float* wq    = (const float*)d_in[1];
    const float* wk    = (const float*)d_in[2];
    const float* wv    = (const float*)d_in[3];
    const float* wproj = (const float*)d_in[4];
    const float* bproj = (const float*)d_in[5];
    const float* w1    = (const float*)d_in[6];
    const float* b1    = (const float*)d_in[7];
    const float* w2    = (const float*)d_in[8];
    const float* b2    = (const float*)d_in[9];
    const float* ln1g  = (const float*)d_in[10];
    const float* ln1b  = (const float*)d_in[11];
    const float* ln2g  = (const float*)d_in[12];
    const float* ln2b  = (const float*)d_in[13];

    // Workspace:
    //  [0,64M)    h,q,k,v (16 MB each) -> later mid (BT x 2048 bf16)
    //  [64,80M)   o (B,T,C bf16)
    //  [80,96M)   h2 (bf16)
    //  [96,102M)  Wt: qkvt[1536][512] | projt[512][512] | w1t[2048][512] | w2t[512][2048]
    //  x1 (f32) lives in d_out (same-thread RMW in final epilogue)
    char* ws = (char*)d_ws;
    bf16*  h    = (bf16*)(ws + 0);
    bf16*  q    = (bf16*)(ws + ((size_t)16 << 20));
    bf16*  k    = (bf16*)(ws + ((size_t)32 << 20));
    bf16*  v    = (bf16*)(ws + ((size_t)48 << 20));   // (B,H,D,T)
    bf16*  mid  = (bf16*)(ws + 0);
    bf16*  o    = (bf16*)(ws + ((size_t)64 << 20));
    bf16*  h2   = (bf16*)(ws + ((size_t)80 << 20));
    bf16*  wt   = (bf16*)(ws + ((size_t)96 << 20));
    bf16*  projt = wt + (size_t)1536 * 512;
    bf16*  w1t   = wt + (size_t)2048 * 512;
    bf16*  w2t   = wt + (size_t)4096 * 512;
    float* x1    = (float*)d_out;

    // 0+1. weight transposes + LN1 in ONE launch (independent work)
    prep_kernel<<<768 + BT, 256, 0, stream>>>(wq, wk, wv, wproj, w1, w2, wt,
                                              x, ln1g, ln1b, h);

    // 2. q|k|v = h @ wqkv  (one N=1536 GEMM; v written (B,H,D,T))
    mfma_gemm<true,  false, true ><<<dim3(12, 128), 256, 0, stream>>>(h, wt, nullptr, nullptr, q, 1536, 512);

    // 3. o = flash-attn(q,k,v) -> (B,T,C); qt-paired grid
    attn_kernel<<<dim3(4, B_ * H_), 256, 0, stream>>>(q, k, v, o);

    // 4. x1 = x + o @ w_proj + b_proj   (x1 = d_out, f32)
    mfma_gemm<false, false, false><<<dim3(4, 128), 256, 0, stream>>>(o, projt, bproj, x, x1, 512, 512);

    // 5. h2 = LN2(x1)
    ln_kernel<<<BT, 256, 0, stream>>>(x1, ln2g, ln2b, h2);

    // 6. mid = relu(h2 @ w1 + b1)
    mfma_gemm<false, true,  true ><<<dim3(16, 128), 256, 0, stream>>>(h2, w1t, b1, nullptr, mid, 2048, 512);

    // 7. out = x1 + mid @ w2 + b2   (in-place on d_out)
    mfma_gemm<false, false, false><<<dim3(4, 128), 256, 0, stream>>>(mid, w2t, b2, x1, (float*)d_out, 512, 2048);
}

// Round 10
// 336.645 us; speedup vs baseline: 1.0852x; 1.0021x over previous
//
#include <hip/hip_runtime.h>
#include <hip/hip_bf16.h>

// Transformer block: B=32 T=512 C=512 H=8 D=64
// Round 14: occupancy + LN micro-round on top of the consolidated round-13.
//  - attn: __launch_bounds__(256,3) -> 3 blocks/CU (LDS 41 KB x3 = 123 <= 160;
//    VGPR 64 << 168 cap). Attn blocks are independent (not barrier-locked),
//    so the 3rd co-resident block adds TLP to hide K/V staging + expf chains
//    (the mechanism that FAILED on lockstep GEMM in round 12 predicts a win
//    here).
//  - LN (both): float2 row loads + packed 2xbf16 stores (pairing t -> 2t,2t+1;
//    mean/var permutation-invariant, exact).
// GEMMs byte-identical to the established optimum (dbuf 2-phase 128^2).

#define B_  32
#define T_  512
#define C_  512
#define H_  8
#define D_  64
#define BT  (B_*T_)      // 16384 rows
#define CF  2048         // 4*C

typedef __hip_bfloat16 bf16;
typedef __attribute__((ext_vector_type(8))) short bf16x8;   // 8 bf16 (4 VGPRs)
typedef __attribute__((ext_vector_type(4))) float f32x4;
typedef __attribute__((ext_vector_type(4))) short short4v;

__device__ __forceinline__ float bf2f(bf16 x) { return __bfloat162float(x); }
__device__ __forceinline__ bf16  f2bf(float x){ return __float2bfloat16(x); }
__device__ __forceinline__ short f2bf_bits(float f){
    bf16 h = __float2bfloat16(f);
    return *reinterpret_cast<short*>(&h);
}
__device__ __forceinline__ float bfbits2f(short s){
    unsigned u = ((unsigned)(unsigned short)s) << 16;
    return __uint_as_float(u);
}
__device__ __forceinline__ unsigned pack2bf(float a, float b){
    return ((unsigned)(unsigned short)f2bf_bits(a)) |
           (((unsigned)(unsigned short)f2bf_bits(b)) << 16);
}

#define AS_G __attribute__((address_space(1)))
#define AS_L __attribute__((address_space(3)))

// ---------------- LN body (shared by prep LN1 path and ln_kernel) ------------
// float2 load per thread (elements 2t, 2t+1), packed 2xbf16 store.
__device__ __forceinline__ void ln_row(const float* __restrict__ xr,
                                       const float* __restrict__ g,
                                       const float* __restrict__ b,
                                       bf16* __restrict__ orow,
                                       float* red, int tid)
{
    const float2 v = *(const float2*)&xr[tid * 2];

    float s = v.x + v.y;
    #pragma unroll
    for (int off = 32; off > 0; off >>= 1) s += __shfl_down(s, off, 64);
    if ((tid & 63) == 0) red[tid >> 6] = s;
    __syncthreads();
    const float mean = (red[0] + red[1] + red[2] + red[3]) * (1.0f / C_);
    __syncthreads();

    const float d0 = v.x - mean, d1 = v.y - mean;
    float vs = d0 * d0 + d1 * d1;
    #pragma unroll
    for (int off = 32; off > 0; off >>= 1) vs += __shfl_down(vs, off, 64);
    if ((tid & 63) == 0) red[tid >> 6] = vs;
    __syncthreads();
    const float var  = (red[0] + red[1] + red[2] + red[3]) * (1.0f / C_);
    const float rstd = rsqrtf(var + 1e-5f);

    const float2 gg = *(const float2*)&g[tid * 2];
    const float2 bb = *(const float2*)&b[tid * 2];
    *(unsigned*)&orow[tid * 2] = pack2bf(d0 * rstd * gg.x + bb.x,
                                         d1 * rstd * gg.y + bb.y);
}

// ---------------- prep: weight transposes (768 blocks) + LN1 (16384 blocks) --
__global__ __launch_bounds__(256) void prep_kernel(const float* __restrict__ wq,
                                                   const float* __restrict__ wk,
                                                   const float* __restrict__ wv,
                                                   const float* __restrict__ wproj,
                                                   const float* __restrict__ w1,
                                                   const float* __restrict__ w2,
                                                   bf16* __restrict__ wt,
                                                   const float* __restrict__ x,
                                                   const float* __restrict__ g,
                                                   const float* __restrict__ b,
                                                   bf16* __restrict__ out)
{
    __shared__ float tl[64][65];
    const int tid = threadIdx.x;

    if (blockIdx.x >= 768) {
        const int row = blockIdx.x - 768;
        ln_row(x + (size_t)row * C_, g, b, out + (size_t)row * C_, &tl[0][0], tid);
        return;
    }

    // ---- transpose path ----
    const int t = blockIdx.x;
    const float* src; int K, Nn, k0, n0; size_t dstoff;
    if (t < 192) {
        const int which = t / 64, w = t % 64, hh = w >> 3, kt = w & 7;
        src = (which == 0 ? wq : which == 1 ? wk : wv) + (size_t)hh * 512 * 64;
        K = 512; Nn = 64; k0 = kt * 64; n0 = 0;
        dstoff = (size_t)(which * 512 + hh * 64) * 512;
    } else if (t < 256) {
        const int i = t - 192;
        src = wproj; K = 512; Nn = 512; n0 = (i & 7) * 64; k0 = (i >> 3) * 64;
        dstoff = (size_t)1536 * 512;
    } else if (t < 512) {
        const int i = t - 256;
        src = w1; K = 512; Nn = 2048; n0 = (i & 31) * 64; k0 = (i >> 5) * 64;
        dstoff = (size_t)2048 * 512;
    } else {
        const int i = t - 512;
        src = w2; K = 2048; Nn = 512; n0 = (i & 7) * 64; k0 = (i >> 3) * 64;
        dstoff = (size_t)2048 * 512 + (size_t)2048 * 512;
    }

    #pragma unroll
    for (int j = 0; j < 16; ++j) {
        const int e = j * 256 + tid, r = e >> 6, c = e & 63;
        tl[r][c] = src[(size_t)(k0 + r) * Nn + n0 + c];
    }
    __syncthreads();
    #pragma unroll
    for (int j = 0; j < 16; ++j) {
        const int e = j * 256 + tid, n = e >> 6, kk = e & 63;
        wt[dstoff + (size_t)(n0 + n) * K + k0 + kk] = f2bf(tl[kk][n]);
    }
}

// ---------------- LayerNorm (LN2): one block per row (C=512) -----------------
__global__ __launch_bounds__(256) void ln_kernel(const float* __restrict__ x,
                                                 const float* __restrict__ g,
                                                 const float* __restrict__ b,
                                                 bf16* __restrict__ out)
{
    __shared__ float red[4];
    const int row = blockIdx.x;
    ln_row(x + (size_t)row * C_, g, b, out + (size_t)row * C_, red, threadIdx.x);
}

// ---------------- MFMA GEMM: dbuf 2-phase 128^2 (established optimum) --------
template<bool QKV, bool RELU, bool OUT_BF16>
__global__ __launch_bounds__(256, 2) void mfma_gemm(const bf16* __restrict__ A,
                                                    const bf16* __restrict__ Bt,
                                                    const float* __restrict__ bias,
                                                    const float* __restrict__ res,
                                                    void* __restrict__ outp,
                                                    int N, int K)
{
    __shared__ __align__(16) bf16 As[2][128 * 64];
    __shared__ __align__(16) bf16 Bs[2][128 * 64];

    const int tid  = threadIdx.x;
    const int wave = tid >> 6, lane = tid & 63;
    const int l16  = lane & 15, quad = lane >> 4;
    const int wm   = wave >> 1, wn = wave & 1;

    const int nwg = gridDim.x * gridDim.y;
    int bid = blockIdx.y * gridDim.x + blockIdx.x;
    bid = (bid & 7) * (nwg >> 3) + (bid >> 3);
    const int tn = (bid % gridDim.x) * 128;
    const int tm = (bid / gridDim.x) * 128;
    const bool vblk = QKV && (tn >= 1024);     // v third of the merged QKV GEMM

    f32x4 acc[4][4];
    #pragma unroll
    for (int i = 0; i < 4; ++i)
        #pragma unroll
        for (int j = 0; j < 4; ++j) acc[i][j] = (f32x4){0.f, 0.f, 0.f, 0.f};

    auto STAGE = [&](int buf, int k0) {
        #pragma unroll
        for (int j = 0; j < 4; ++j) {
            const int g = j * 256 + tid;
            const int row = g >> 3, phys = g & 7;
            const int c = phys ^ (row & 7);          // logical 16B chunk
            __builtin_amdgcn_global_load_lds((const AS_G void*)(A  + (size_t)(tm + row) * K + k0 + c * 8),
                                             (AS_L void*)&As[buf][(size_t)g * 8], 16, 0, 0);
            __builtin_amdgcn_global_load_lds((const AS_G void*)(Bt + (size_t)(tn + row) * K + k0 + c * 8),
                                             (AS_L void*)&Bs[buf][(size_t)g * 8], 16, 0, 0);
        }
    };

    STAGE(0, 0);
    __syncthreads();

    int cur = 0;
    for (int k0 = 0; k0 < K; k0 += 64) {
        if (k0 + 64 < K) STAGE(cur ^ 1, k0 + 64);   // prefetch next tile

        #pragma unroll
        for (int half = 0; half < 2; ++half) {
            bf16x8 af[4], bfr[4];
            #pragma unroll
            for (int mf = 0; mf < 4; ++mf) {
                const int r = wm * 64 + mf * 16 + l16;
                const int p = (half * 4 + quad) ^ (r & 7);
                af[mf] = *(const bf16x8*)&As[cur][r * 64 + p * 8];
            }
            #pragma unroll
            for (int nf = 0; nf < 4; ++nf) {
                const int r = wn * 64 + nf * 16 + l16;
                const int p = (half * 4 + quad) ^ (r & 7);
                bfr[nf] = *(const bf16x8*)&Bs[cur][r * 64 + p * 8];
            }
            if (vblk) {
                #pragma unroll
                for (int mf = 0; mf < 4; ++mf)
                    #pragma unroll
                    for (int nf = 0; nf < 4; ++nf)
                        acc[mf][nf] = __builtin_amdgcn_mfma_f32_16x16x32_bf16(af[mf], bfr[nf], acc[mf][nf], 0, 0, 0);
            } else {
                #pragma unroll
                for (int mf = 0; mf < 4; ++mf)
                    #pragma unroll
                    for (int nf = 0; nf < 4; ++nf)
                        acc[mf][nf] = __builtin_amdgcn_mfma_f32_16x16x32_bf16(bfr[nf], af[mf], acc[mf][nf], 0, 0, 0);
            }
        }

        __syncthreads();
        cur ^= 1;
    }

    if (QKV) {
        bf16* qkv = (bf16*)outp;                 // q base; k at +8M elems, v at +16M
        if (!vblk) {
            const int which = tn >> 9;           // 0=q, 1=k
            bf16* dst = qkv + (size_t)which * (8u << 20);
            #pragma unroll
            for (int mf = 0; mf < 4; ++mf) {
                const int m = tm + wm * 64 + mf * 16 + l16;   // token (C^T: col=m)
                const int bb = m >> 9, t = m & 511;
                #pragma unroll
                for (int nf = 0; nf < 4; ++nf) {
                    const int nb = tn + wn * 64 + nf * 16 + quad * 4;
                    const int hh = (nb >> 6) & 7, dd = nb & 63;
                    short4v pk;
                    #pragma unroll
                    for (int r = 0; r < 4; ++r) pk[r] = f2bf_bits(acc[mf][nf][r]);
                    *(short4v*)&dst[((size_t)(bb * 8 + hh) * 512 + t) * 64 + dd] = pk;
                }
            }
        } else {
            bf16* dst = qkv + (size_t)2 * (8u << 20);
            #pragma unroll
            for (int mf = 0; mf < 4; ++mf) {
                const int mb = tm + wm * 64 + mf * 16 + quad * 4;   // token base
                const int bb = mb >> 9, t = mb & 511;
                #pragma unroll
                for (int nf = 0; nf < 4; ++nf) {
                    const int n = tn + wn * 64 + nf * 16 + l16;
                    const int hh = (n >> 6) & 7, dd = n & 63;
                    short4v pk;
                    #pragma unroll
                    for (int r = 0; r < 4; ++r) pk[r] = f2bf_bits(acc[mf][nf][r]);
                    *(short4v*)&dst[((size_t)(bb * 8 + hh) * 64 + dd) * 512 + t] = pk;
                }
            }
        }
    } else {
        #pragma unroll
        for (int mf = 0; mf < 4; ++mf) {
            const int m = tm + wm * 64 + mf * 16 + l16;             // C^T: col=m
            #pragma unroll
            for (int nf = 0; nf < 4; ++nf) {
                const int nb = tn + wn * 64 + nf * 16 + quad * 4;   // 4 consecutive n
                f32x4 a = acc[mf][nf];
                if (bias) a += *(const f32x4*)&bias[nb];
                if (RELU) {
                    #pragma unroll
                    for (int r = 0; r < 4; ++r) a[r] = fmaxf(a[r], 0.0f);
                }
                if (res)  a += *(const f32x4*)&res[(size_t)m * N + nb];
                if (OUT_BF16) {
                    short4v pk;
                    #pragma unroll
                    for (int r = 0; r < 4; ++r) pk[r] = f2bf_bits(a[r]);
                    *(short4v*)&((bf16*)outp)[(size_t)m * N + nb] = pk;
                } else {
                    *(f32x4*)&((float*)outp)[(size_t)m * N + nb] = a;
                }
            }
        }
    }
}

// ---------------- Flash attention: qt-paired + setprio, 3 blocks/CU ----------
#define ATTN_TILE(qa, m_i, l_i, Of, qw, qtT)                                          \
  do {                                                                                \
    f32x4 Sf[4];                                                                      \
    __builtin_amdgcn_s_setprio(1);                                                    \
    _Pragma("unroll")                                                                 \
    for (int kf = 0; kf < 4; ++kf) {                                                  \
        const int row = kf * 16 + l16;                                                \
        bf16x8 b0 = *(const bf16x8*)&Ks[cur][row * 64 + ((quad ^ (row & 7)) * 8)];    \
        bf16x8 b1 = *(const bf16x8*)&Ks[cur][row * 64 + (((4 + quad) ^ (row & 7)) * 8)]; \
        f32x4 z = (f32x4){0.f, 0.f, 0.f, 0.f};                                        \
        z = __builtin_amdgcn_mfma_f32_16x16x32_bf16(qa[0], b0, z, 0, 0, 0);           \
        z = __builtin_amdgcn_mfma_f32_16x16x32_bf16(qa[1], b1, z, 0, 0, 0);           \
        Sf[kf] = z;                                                                   \
    }                                                                                 \
    __builtin_amdgcn_s_setprio(0);                                                    \
    if (kt == qtT) {                                                                  \
        _Pragma("unroll")                                                             \
        for (int kf = 0; kf < 4; ++kf)                                                \
            _Pragma("unroll")                                                         \
            for (int r = 0; r < 4; ++r)                                               \
                if (kt * 64 + kf * 16 + l16 > (qw) + quad * 4 + r) Sf[kf][r] = -1e30f;\
    }                                                                                 \
    float mnew[4], alpha[4];                                                          \
    _Pragma("unroll")                                                                 \
    for (int r = 0; r < 4; ++r) {                                                     \
        float v = fmaxf(fmaxf(Sf[0][r], Sf[1][r]), fmaxf(Sf[2][r], Sf[3][r]));        \
        v = fmaxf(v, __shfl_xor(v, 1, 64));                                           \
        v = fmaxf(v, __shfl_xor(v, 2, 64));                                           \
        v = fmaxf(v, __shfl_xor(v, 4, 64));                                           \
        v = fmaxf(v, __shfl_xor(v, 8, 64));                                           \
        mnew[r]   = fmaxf(m_i[r], v);                                                 \
        alpha[r]  = __expf(m_i[r] - mnew[r]);                                         \
        m_i[r]    = mnew[r];                                                          \
    }                                                                                 \
    float rs[4] = {0.f, 0.f, 0.f, 0.f};                                               \
    _Pragma("unroll")                                                                 \
    for (int kf = 0; kf < 4; ++kf) {                                                  \
        _Pragma("unroll")                                                             \
        for (int r = 0; r < 4; ++r) {                                                 \
            float p = __expf(Sf[kf][r] - mnew[r]);                                    \
            rs[r] += p;                                                               \
            Pw[wave][quad * 4 + r][kf * 16 + l16] = f2bf(p);                          \
        }                                                                             \
    }                                                                                 \
    _Pragma("unroll")                                                                 \
    for (int r = 0; r < 4; ++r) {                                                     \
        rs[r] += __shfl_xor(rs[r], 1, 64);                                            \
        rs[r] += __shfl_xor(rs[r], 2, 64);                                            \
        rs[r] += __shfl_xor(rs[r], 4, 64);                                            \
        rs[r] += __shfl_xor(rs[r], 8, 64);                                            \
        l_i[r] = l_i[r] * alpha[r] + rs[r];                                           \
    }                                                                                 \
    _Pragma("unroll")                                                                 \
    for (int f = 0; f < 4; ++f)                                                       \
        _Pragma("unroll")                                                             \
        for (int r = 0; r < 4; ++r)                                                   \
            Of[f][r] *= alpha[r];                                                     \
    bf16x8 pa0 = *(const bf16x8*)&Pw[wave][l16][quad * 8];                            \
    bf16x8 pa1 = *(const bf16x8*)&Pw[wave][l16][32 + quad * 8];                       \
    __builtin_amdgcn_s_setprio(1);                                                    \
    _Pragma("unroll")                                                                 \
    for (int f = 0; f < 4; ++f) {                                                     \
        const int vrow = f * 16 + l16;                                                \
        bf16x8 vb0 = *(const bf16x8*)&Vt[cur][vrow * 64 + ((quad ^ (vrow & 7)) * 8)]; \
        bf16x8 vb1 = *(const bf16x8*)&Vt[cur][vrow * 64 + (((4 + quad) ^ (vrow & 7)) * 8)]; \
        Of[f] = __builtin_amdgcn_mfma_f32_16x16x32_bf16(pa0, vb0, Of[f], 0, 0, 0);    \
        Of[f] = __builtin_amdgcn_mfma_f32_16x16x32_bf16(pa1, vb1, Of[f], 0, 0, 0);    \
    }                                                                                 \
    __builtin_amdgcn_s_setprio(0);                                                    \
  } while (0)

__global__ __launch_bounds__(256, 3) void attn_kernel(const bf16* __restrict__ q,
                                                      const bf16* __restrict__ kM,
                                                      const bf16* __restrict__ vT,
                                                      bf16* __restrict__ o)
{
    __shared__ __align__(16) bf16 Ks[2][64 * 64];
    __shared__ __align__(16) bf16 Vt[2][64 * 64];
    __shared__ __align__(16) bf16 Pw[4][16][72];

    const int tid  = threadIdx.x;
    const int wave = tid >> 6, lane = tid & 63;
    const int l16  = lane & 15, quad = lane >> 4;

    const int nwg = gridDim.x * gridDim.y;
    int bid = blockIdx.y * gridDim.x + blockIdx.x;
    bid = (bid & 7) * (nwg >> 3) + (bid >> 3);
    const int pair = bid & 3;
    const int bh   = bid >> 2;

    const int qt0 = pair, qt1 = 7 - pair;
    const int qw0 = qt0 * 64 + wave * 16;
    const int qw1 = qt1 * 64 + wave * 16;

    const float scale = 0.04419417382415922f;  // C^-0.5 (reference uses n_embd)
    bf16x8 qa0[2], qa1[2];
    #pragma unroll
    for (int c = 0; c < 2; ++c) {
        bf16x8 t0 = *(const bf16x8*)(q + ((size_t)bh * T_ + qw0 + l16) * 64 + c * 32 + quad * 8);
        bf16x8 t1 = *(const bf16x8*)(q + ((size_t)bh * T_ + qw1 + l16) * 64 + c * 32 + quad * 8);
        #pragma unroll
        for (int j = 0; j < 8; ++j) {
            t0[j] = f2bf_bits(bfbits2f(t0[j]) * scale);
            t1[j] = f2bf_bits(bfbits2f(t1[j]) * scale);
        }
        qa0[c] = t0; qa1[c] = t1;
    }

    float m0[4], l0[4], m1[4], l1[4];
    f32x4 O0[4], O1[4];
    #pragma unroll
    for (int r = 0; r < 4; ++r) { m0[r] = -1e30f; l0[r] = 0.f; m1[r] = -1e30f; l1[r] = 0.f; }
    #pragma unroll
    for (int f = 0; f < 4; ++f) { O0[f] = (f32x4){0.f,0.f,0.f,0.f}; O1[f] = (f32x4){0.f,0.f,0.f,0.f}; }

    auto STAGE = [&](int buf, int kt) {
        const int k0 = kt * 64;
        #pragma unroll
        for (int j = 0; j < 2; ++j) {
            const int g = j * 256 + tid;
            const int row = g >> 3, phys = g & 7;
            const int c = phys ^ (row & 7);
            __builtin_amdgcn_global_load_lds((const AS_G void*)(kM + ((size_t)bh * T_ + k0 + row) * 64 + c * 8),
                                             (AS_L void*)&Ks[buf][(size_t)g * 8], 16, 0, 0);
            __builtin_amdgcn_global_load_lds((const AS_G void*)(vT + ((size_t)bh * 64 + row) * T_ + k0 + c * 8),
                                             (AS_L void*)&Vt[buf][(size_t)g * 8], 16, 0, 0);
        }
    };

    STAGE(0, 0);
    __syncthreads();

    int cur = 0;
    for (int kt = 0; kt <= qt1; ++kt) {
        if (kt < qt1) STAGE(cur ^ 1, kt + 1);

        if (kt <= qt0) ATTN_TILE(qa0, m0, l0, O0, qw0, qt0);
        ATTN_TILE(qa1, m1, l1, O1, qw1, qt1);

        __syncthreads();
        cur ^= 1;
    }

    const int b = bh >> 3, hh = bh & 7;
    #pragma unroll
    for (int r = 0; r < 4; ++r) {
        const float inv0 = 1.0f / l0[r];
        const float inv1 = 1.0f / l1[r];
        const int t0 = qw0 + quad * 4 + r;
        const int t1 = qw1 + quad * 4 + r;
        #pragma unroll
        for (int f = 0; f < 4; ++f) {
            o[((size_t)b * T_ + t0) * C_ + hh * 64 + f * 16 + l16] = f2bf(O0[f][r] * inv0);
            o[((size_t)b * T_ + t1) * C_ + hh * 64 + f * 16 + l16] = f2bf(O1[f][r] * inv1);
        }
    }
}

// -----------------------------------------------------------------------------
extern "C" void kernel_launch(void* const* d_in, const int* in_sizes, int n_in,
                              void* d_out, int out_size, void* d_ws, size_t ws_size,
                              hipStream_t stream)
{
    const float* x     = (const float*)d_in[0];
    const float* wq    = (const float*)d_in[1];
    const float* wk    = (const float*)d_in[2];
    const float* wv    = (const float*)d_in[3];
    const float* wproj = (const float*)d_in[4];
    const float* bproj = (const float*)d_in[5];
    const float* w1    = (const float*)d_in[6];
    const float* b1    = (const float*)d_in[7];
    const float* w2    = (const float*)d_in[8];
    const float* b2    = (const float*)d_in[9];
    const float* ln1g  = (const float*)d_in[10];
    const float* ln1b  = (const float*)d_in[11];
    const float* ln2g  = (const float*)d_in[12];
    const float* ln2b  = (const float*)d_in[13];

    // Workspace:
    //  [0,64M)    h,q,k,v (16 MB each) -> later mid (BT x 2048 bf16)
    //  [64,80M)   o (B,T,C bf16)
    //  [80,96M)   h2 (bf16)
    //  [96,102M)  Wt: qkvt[1536][512] | projt[512][512] | w1t[2048][512] | w2t[512][2048]
    //  x1 (f32) lives in d_out (same-thread RMW in final epilogue)
    char* ws = (char*)d_ws;
    bf16*  h    = (bf16*)(ws + 0);
    bf16*  q    = (bf16*)(ws + ((size_t)16 << 20));
    bf16*  k    = (bf16*)(ws + ((size_t)32 << 20));
    bf16*  v    = (bf16*)(ws + ((size_t)48 << 20));   // (B,H,D,T)
    bf16*  mid  = (bf16*)(ws + 0);
    bf16*  o    = (bf16*)(ws + ((size_t)64 << 20));
    bf16*  h2   = (bf16*)(ws + ((size_t)80 << 20));
    bf16*  wt   = (bf16*)(ws + ((size_t)96 << 20));
    bf16*  projt = wt + (size_t)1536 * 512;
    bf16*  w1t   = wt + (size_t)2048 * 512;
    bf16*  w2t   = wt + (size_t)4096 * 512;
    float* x1    = (float*)d_out;

    // 0+1. weight transposes + LN1 in ONE launch (independent work)
    prep_kernel<<<768 + BT, 256, 0, stream>>>(wq, wk, wv, wproj, w1, w2, wt,
                                              x, ln1g, ln1b, h);

    // 2. q|k|v = h @ wqkv  (one N=1536 GEMM; v written (B,H,D,T))
    mfma_gemm<true,  false, true ><<<dim3(12, 128), 256, 0, stream>>>(h, wt, nullptr, nullptr, q, 1536, 512);

    // 3. o = flash-attn(q,k,v) -> (B,T,C); qt-paired grid, 3 blocks/CU
    attn_kernel<<<dim3(4, B_ * H_), 256, 0, stream>>>(q, k, v, o);

    // 4. x1 = x + o @ w_proj + b_proj   (x1 = d_out, f32)
    mfma_gemm<false, false, false><<<dim3(4, 128), 256, 0, stream>>>(o, projt, bproj, x, x1, 512, 512);

    // 5. h2 = LN2(x1)
    ln_kernel<<<BT, 256, 0, stream>>>(x1, ln2g, ln2b, h2);

    // 6. mid = relu(h2 @ w1 + b1)
    mfma_gemm<false, true,  true ><<<dim3(16, 128), 256, 0, stream>>>(h2, w1t, b1, nullptr, mid, 2048, 512);

    // 7. out = x1 + mid @ w2 + b2   (in-place on d_out)
    mfma_gemm<false, false, false><<<dim3(4, 128), 256, 0, stream>>>(mid, w2t, b2, x1, (float*)d_out, 512, 2048);
}